// Round 13
// baseline (268.101 us; speedup 1.0000x reference)
//
#include <hip/hip_runtime.h>

#define B_SZ 4
#define IN_CH 64
#define OUT_CH 128
#define NHI 163842
#define NLO 40962
#define EPS_GN 1e-5f
#define SLOPE 0.2f

typedef __attribute__((ext_vector_type(8))) short short8;
typedef __attribute__((ext_vector_type(16))) float f32x16;

__device__ inline ushort f2bf(float f) {
    union { float f; unsigned u; } v; v.f = f;
    unsigned r = v.u + 0x7FFF + ((v.u >> 16) & 1);
    return (ushort)(r >> 16);
}
__device__ inline float bf2f(ushort h) {
    union { unsigned u; float f; } v; v.u = ((unsigned)h) << 16;
    return v.f;
}

// async global->LDS, 16B per lane; LDS dest = uniform base + lane*16
__device__ inline void glds16(const ushort* g, ushort* l) {
    typedef __attribute__((address_space(1))) const void gv;
    typedef __attribute__((address_space(3))) void lv;
    __builtin_amdgcn_global_load_lds((gv*)g, (lv*)l, 16, 0, 0);
}

// ---------------------------------------------------------------------------
// 1) Transpose x: (B,64,NHI) f32 -> xT (B,NHI,64) bf16
// ---------------------------------------------------------------------------
__global__ void k_transpose_x(const float* __restrict__ x, ushort* __restrict__ xT) {
    __shared__ float t[64][65];
    const int b   = blockIdx.y;
    const int n0  = blockIdx.x * 64;
    const int tid = threadIdx.x;
    const int nq  = tid & 15;
    const int c0  = tid >> 4;
    const bool full = (n0 + 64) <= NHI;
    if (full) {
#pragma unroll
        for (int r = 0; r < 4; ++r) {
            int c = c0 + r * 16;
            float4 v = *(const float4*)&x[((long)b * IN_CH + c) * NHI + n0 + nq * 4];
            t[c][nq * 4 + 0] = v.x; t[c][nq * 4 + 1] = v.y;
            t[c][nq * 4 + 2] = v.z; t[c][nq * 4 + 3] = v.w;
        }
    } else {
        for (int r = 0; r < 4; ++r) {
            int c = c0 + r * 16;
            for (int e = 0; e < 4; ++e) {
                int n = n0 + nq * 4 + e;
                t[c][nq * 4 + e] = (n < NHI) ? x[((long)b * IN_CH + c) * NHI + n] : 0.f;
            }
        }
    }
    __syncthreads();
    const int n  = tid >> 2;
    const int cc = (tid & 3) * 16;
    if (n0 + n < NHI) {
        short8 o0, o1;
#pragma unroll
        for (int e = 0; e < 8; ++e) {
            o0[e] = (short)f2bf(t[cc + e][n]);
            o1[e] = (short)f2bf(t[cc + 8 + e][n]);
        }
        ushort* p = &xT[((long)b * NHI + n0 + n) * 64 + cc];
        *(short8*)p = o0;
        *(short8*)(p + 8) = o1;
    }
}

// ---------------------------------------------------------------------------
// 2) Pre-tile weights W (O=128, K) f32 -> Wb bf16 in the conv LDS image:
//    Wb[step][kg(8)][o(128)][e(8)]  where k = step*64 + kg*8 + e
// ---------------------------------------------------------------------------
__global__ void k_prep_w(const float* __restrict__ W, ushort* __restrict__ Wb, int K) {
    int i = blockIdx.x * 256 + threadIdx.x;
    if (i >= K * 128) return;
    int k = i / 128, o = i % 128;
    int step = k >> 6, kk = k & 63, kg = kk >> 3, e = kk & 7;
    Wb[(((long)(step * 8 + kg) * 128 + o) * 8) + e] = f2bf(W[(long)o * K + k]);
}

// ---------------------------------------------------------------------------
// 3) Mean pool
// ---------------------------------------------------------------------------
__global__ void k_pool(const ushort* __restrict__ xT, const int* __restrict__ pn,
                       ushort* __restrict__ h1) {
    long t = (long)blockIdx.x * 256 + threadIdx.x;
    const long total = (long)B_SZ * NLO * 8;
    if (t >= total) return;
    int  cq = (int)(t & 7);
    long bn = t >> 3;
    int  n  = (int)(bn % NLO);
    int  b  = (int)(bn / NLO);
    float acc[8] = {};
#pragma unroll
    for (int j = 0; j < 7; ++j) {
        int idx = pn[n * 7 + j];
        short8 v = *(const short8*)&xT[((long)b * NHI + idx) * 64 + cq * 8];
#pragma unroll
        for (int e = 0; e < 8; ++e) acc[e] += bf2f((ushort)v[e]);
    }
    short8 o;
#pragma unroll
    for (int e = 0; e < 8; ++e) o[e] = (short)f2bf(acc[e] * (1.f / 7.f));
    *(short8*)&h1[bn * 64 + cq * 8] = o;
}

// Swizzled A-image index (R11-verified conflict-free: writes 2-way max (free),
// reads a permutation of 8 distinct bank-quads per 8-lane phase).
__device__ inline int aidx(int kg, int nn) {
    return (kg * 128 + (nn ^ (kg << 1))) * 8;
}

// ---------------------------------------------------------------------------
// 4) MFMA one-ring conv — R11 schedule, WAVE TILE 64x64 (was 32x64).
//    Per kg: 2 A-reads + 2 B-reads feed 4 MFMAs -> 1.0 KB LDS/MFMA (was 1.5).
//    The conv family is LDS-read-BW bound (cap ~ LDS_BW / (0.5*KB_per_MFMA)),
//    so this raises the MfmaUtil ceiling ~1.5x. Block 128 nodes x 128 outs,
//    256 threads (4 waves, 2x2), BK=64, dbuf, ONE barrier/step.
//    A: coalesced gather (2 thr/row, 64B each) -> regs -> swizzled LDS.
//    B: global_load_lds DMA (no VGPR round-trip), linear image.
// ---------------------------------------------------------------------------
template <int CIN>
__global__ __launch_bounds__(256, 2)
void k_conv_mfma(const ushort* __restrict__ src, const int* __restrict__ nbr,
                 const ushort* __restrict__ Wb, const float* __restrict__ bias,
                 ushort* __restrict__ out, float* __restrict__ part) {
    constexpr int NSTEP = 7 * CIN / 64;
    __shared__ ushort Asm[2][8192];   // 16KB/buf, swizzled [kg][nn][e]
    __shared__ ushort Bsm[2][8192];   // 16KB/buf, linear   [kg][o][e]
    __shared__ float  red[4][2][2];

    const int b     = blockIdx.y;
    const int n0    = blockIdx.x * 128;
    const int tid   = threadIdx.x;
    const int lane  = tid & 63;
    const int wave  = tid >> 6;              // 0..3
    const int wr    = wave >> 1, wc = wave & 1;
    const int l31   = lane & 31;
    const int khalf = lane >> 5;

    // A staging: 2 threads per node row, 64B (4 x b128) each
    const int s_nn = tid >> 1;               // 0..127
    const int s_h  = tid & 1;                // kg half: kg = s_h*4 + i
    const int nrow = min(n0 + s_nn, NLO - 1);
    const int* nbr_row = &nbr[nrow * 7];

    const long srcb = (long)b * NLO * CIN;
    f32x16 acc[2][2] = {};
    short8 a[4];

    auto loadA = [&](int t) {
        int j, cb;
        if (CIN == 64) { j = t; cb = 0; }
        else           { j = t >> 1; cb = (t & 1) * 64; }
        const ushort* sp = &src[srcb + (long)nbr_row[j] * CIN + cb + s_h * 32];
#pragma unroll
        for (int i = 0; i < 4; ++i) a[i] = *(const short8*)(sp + i * 8);
    };
    auto writeA = [&](int buf) {
#pragma unroll
        for (int i = 0; i < 4; ++i)
            *(short8*)&Asm[buf][aidx(s_h * 4 + i, s_nn)] = a[i];
    };
    auto gldsB = [&](int t, int buf) {
#pragma unroll
        for (int i = 0; i < 4; ++i)
            glds16(&Wb[(long)t * 8192 + (i * 256 + tid) * 8],
                   &Bsm[buf][(i * 256 + tid) * 8]);
    };

    // prologue: B(0) DMA; A(0) -> regs
    gldsB(0, 0);
    loadA(0);

#pragma unroll
    for (int step = 0; step < NSTEP; ++step) {
        const int cur = step & 1;
        writeA(cur);        // a[] holds A(step)
        __syncthreads();    // drains B(step) DMA + A(step) writes
        if (step + 1 < NSTEP) {
            gldsB(step + 1, cur ^ 1);   // DMA in flight across MFMA cluster
            loadA(step + 1);            // gather prefetch
        }
#pragma unroll
        for (int kh = 0; kh < 4; ++kh) {
            const int kg = 2 * kh + khalf;
            short8 A0 = *(const short8*)&Asm[cur][aidx(kg, wr * 64 + l31)];
            short8 A1 = *(const short8*)&Asm[cur][aidx(kg, wr * 64 + 32 + l31)];
            short8 B0 = *(const short8*)&Bsm[cur][(kg * 128 + wc * 64 + l31) * 8];
            short8 B1 = *(const short8*)&Bsm[cur][(kg * 128 + wc * 64 + 32 + l31) * 8];
            acc[0][0] = __builtin_amdgcn_mfma_f32_32x32x16_bf16(A0, B0, acc[0][0], 0, 0, 0);
            acc[0][1] = __builtin_amdgcn_mfma_f32_32x32x16_bf16(A0, B1, acc[0][1], 0, 0, 0);
            acc[1][0] = __builtin_amdgcn_mfma_f32_32x32x16_bf16(A1, B0, acc[1][0], 0, 0, 0);
            acc[1][1] = __builtin_amdgcn_mfma_f32_32x32x16_bf16(A1, B1, acc[1][1], 0, 0, 0);
        }
        // single barrier per step: next iter writes the other buffer.
    }

    // epilogue: bias, bf16 store, per-block GroupNorm partials (R6-verified)
    float bia[2];
#pragma unroll
    for (int n = 0; n < 2; ++n) bia[n] = bias[wc * 64 + n * 32 + l31];
    float s[2] = {}, q[2] = {};
#pragma unroll
    for (int m = 0; m < 2; ++m)
#pragma unroll
        for (int n = 0; n < 2; ++n)
#pragma unroll
            for (int r = 0; r < 16; ++r) {
                int crow = (r & 3) + 8 * (r >> 2) + 4 * khalf;
                int row  = n0 + wr * 64 + m * 32 + crow;
                float v  = acc[m][n][r] + bia[n];
                if (row < NLO) {
                    out[((long)b * NLO + row) * 128 + wc * 64 + n * 32 + l31] = f2bf(v);
                    s[n] += v; q[n] += v * v;
                }
            }
#pragma unroll
    for (int n = 0; n < 2; ++n)
#pragma unroll
        for (int off = 32; off > 0; off >>= 1) {
            s[n] += __shfl_down(s[n], off);
            q[n] += __shfl_down(q[n], off);
        }
    if (lane == 0) {
#pragma unroll
        for (int n = 0; n < 2; ++n) { red[wave][n][0] = s[n]; red[wave][n][1] = q[n]; }
    }
    __syncthreads();
    if (tid < 8) {
        int g = tid >> 1, isq = tid & 1;          // g = wc*2 + n
        int gwc = g >> 1, gn = g & 1;
        float v = red[gwc][gn][isq] + red[2 + gwc][gn][isq];
        part[(((long)b * gridDim.x + blockIdx.x) * 4 + g) * 2 + isq] = v;
    }
}

// ---------------------------------------------------------------------------
// 5) Finalize stats -> per (b,c) scale/shift. One block per (b,g).
// ---------------------------------------------------------------------------
__global__ void k_finalize(const float* __restrict__ part, int nblk,
                           const float* __restrict__ w, const float* __restrict__ bb,
                           float* __restrict__ scale, float* __restrict__ shift) {
    const int b = blockIdx.x >> 2, g = blockIdx.x & 3;
    const int tid = threadIdx.x;
    float s = 0.f, ss = 0.f;
    for (int k = tid; k < nblk; k += 256) {
        s  += part[(((long)b * nblk + k) * 4 + g) * 2 + 0];
        ss += part[(((long)b * nblk + k) * 4 + g) * 2 + 1];
    }
#pragma unroll
    for (int off = 32; off > 0; off >>= 1) {
        s += __shfl_down(s, off); ss += __shfl_down(ss, off);
    }
    __shared__ float red[8];
    __shared__ float fin[2];
    const int wave = tid >> 6, lane = tid & 63;
    if (lane == 0) { red[wave * 2] = s; red[wave * 2 + 1] = ss; }
    __syncthreads();
    if (tid == 0) {
        float as = red[0] + red[2] + red[4] + red[6];
        float aq = red[1] + red[3] + red[5] + red[7];
        const float cnt = 32.f * NLO;
        float mu  = as / cnt;
        float var = aq / cnt - mu * mu;
        fin[0] = mu; fin[1] = rsqrtf(var + EPS_GN);
    }
    __syncthreads();
    if (tid < 32) {
        int c = g * 32 + tid;
        float sc = fin[1] * w[c];
        scale[b * 128 + c] = sc;
        shift[b * 128 + c] = bb[c] - fin[0] * sc;
    }
}

// ---------------------------------------------------------------------------
// 6) Elementwise gn+leakyrelu: y (B,NLO,128) bf16 -> yp bf16
// ---------------------------------------------------------------------------
__global__ void k_gnapply(const ushort* __restrict__ y, const float* __restrict__ sc,
                          const float* __restrict__ sh, ushort* __restrict__ yp) {
    long t = (long)blockIdx.x * 256 + threadIdx.x;
    const long total = (long)B_SZ * NLO * 16;
    if (t >= total) return;
    int  c8 = (int)(t & 15);
    long bn = t >> 4;
    int  b  = (int)(bn / NLO);
    short8 v = *(const short8*)&y[bn * 128 + c8 * 8];
    short8 o;
#pragma unroll
    for (int e = 0; e < 8; ++e) {
        int c = c8 * 8 + e;
        float f = bf2f((ushort)v[e]) * sc[b * 128 + c] + sh[b * 128 + c];
        f = fmaxf(f, SLOPE * f);
        o[e] = (short)f2bf(f);
    }
    *(short8*)&yp[bn * 128 + c8 * 8] = o;
}

// ---------------------------------------------------------------------------
// 7) Output: gn2 + leakyrelu + transpose (B,N,128) bf16 -> (B,128,N) f32
// ---------------------------------------------------------------------------
__global__ void k_output(const ushort* __restrict__ y2, const float* __restrict__ scale,
                         const float* __restrict__ shift, float* __restrict__ out) {
    __shared__ float t[32][129];
    const int b   = blockIdx.y;
    const int n0  = blockIdx.x * 32;
    const int tid = threadIdx.x;
    const float* scb = &scale[b * 128];
    const float* shb = &shift[b * 128];
    const int c8 = (tid & 15) * 8;
#pragma unroll
    for (int r = 0; r < 2; ++r) {
        int nn = (tid >> 4) + r * 16;
        int n  = n0 + nn;
        if (n < NLO) {
            short8 v = *(const short8*)&y2[((long)b * NLO + n) * 128 + c8];
#pragma unroll
            for (int e = 0; e < 8; ++e) {
                int c = c8 + e;
                float f = bf2f((ushort)v[e]) * scb[c] + shb[c];
                t[nn][c] = fmaxf(f, SLOPE * f);
            }
        } else {
#pragma unroll
            for (int e = 0; e < 8; ++e) t[nn][c8 + e] = 0.f;
        }
    }
    __syncthreads();
    const int n4 = (tid & 7) * 4;
    const bool full = (n0 + 32) <= NLO;
#pragma unroll
    for (int r = 0; r < 4; ++r) {
        int c = (tid >> 3) + r * 32;
        long o = ((long)b * 128 + c) * NLO + n0 + n4;
        if (full) {
            float2 v0 = make_float2(t[n4][c], t[n4 + 1][c]);
            float2 v1 = make_float2(t[n4 + 2][c], t[n4 + 3][c]);
            *(float2*)&out[o]     = v0;
            *(float2*)&out[o + 2] = v1;
        } else {
            for (int e = 0; e < 4; ++e)
                if (n0 + n4 + e < NLO) out[o + e] = t[n4 + e][c];
        }
    }
}

// ---------------------------------------------------------------------------
// Launch
// ---------------------------------------------------------------------------
extern "C" void kernel_launch(void* const* d_in, const int* in_sizes, int n_in,
                              void* d_out, int out_size, void* d_ws, size_t ws_size,
                              hipStream_t stream) {
    const float* x   = (const float*)d_in[0];
    const int*   pn  = (const int*)d_in[1];
    const int*   cn  = (const int*)d_in[2];
    const float* W1  = (const float*)d_in[3];
    const float* b1  = (const float*)d_in[4];
    const float* g1w = (const float*)d_in[5];
    const float* g1b = (const float*)d_in[6];
    const float* W2  = (const float*)d_in[7];
    const float* b2  = (const float*)d_in[8];
    const float* g2w = (const float*)d_in[9];
    const float* g2b = (const float*)d_in[10];
    float* out = (float*)d_out;
    char*  base = (char*)d_ws;

    ushort* xT  = (ushort*)(base + 0);           // 83,887,104 B
    ushort* y1  = (ushort*)(base + 0);           // reuse (xT dead after pool)
    ushort* y1p = (ushort*)(base + 44000000);
    ushort* h1  = (ushort*)(base + 88000000);
    ushort* y2  = (ushort*)(base + 110000000);
    ushort* wb1 = (ushort*)(base + 152000000);
    ushort* wb2 = (ushort*)(base + 152200000);
    float*  p1  = (float*)(base + 152500000);
    float*  p2  = (float*)(base + 152600000);
    float*  sc1 = (float*)(base + 152700000);
    float*  sh1 = sc1 + 512;
    float*  sc2 = (float*)(base + 152710000);
    float*  sh2 = sc2 + 512;

    const int NBLK = (NLO + 127) / 128;  // 321 conv blocks per batch

    k_transpose_x<<<dim3((NHI + 63) / 64, B_SZ), 256, 0, stream>>>(x, xT);
    k_prep_w<<<(448 * 128 + 255) / 256, 256, 0, stream>>>(W1, wb1, 448);
    k_prep_w<<<(896 * 128 + 255) / 256, 256, 0, stream>>>(W2, wb2, 896);
    k_pool<<<(int)(((long)B_SZ * NLO * 8 + 255) / 256), 256, 0, stream>>>(xT, pn, h1);
    k_conv_mfma<64><<<dim3(NBLK, B_SZ), 256, 0, stream>>>(h1, cn, wb1, b1, y1, p1);
    k_finalize<<<16, 256, 0, stream>>>(p1, NBLK, g1w, g1b, sc1, sh1);
    k_gnapply<<<(int)(((long)B_SZ * NLO * 16 + 255) / 256), 256, 0, stream>>>(y1, sc1, sh1, y1p);
    k_conv_mfma<128><<<dim3(NBLK, B_SZ), 256, 0, stream>>>(y1p, cn, wb2, b2, y2, p2);
    k_finalize<<<16, 256, 0, stream>>>(p2, NBLK, g2w, g2b, sc2, sh2);
    k_output<<<dim3((NLO + 31) / 32, B_SZ), 256, 0, stream>>>(y2, sc2, sh2, out);
}

// Round 14
// 243.379 us; speedup vs baseline: 1.1016x; 1.1016x over previous
//
#include <hip/hip_runtime.h>

#define B_SZ 4
#define IN_CH 64
#define OUT_CH 128
#define NHI 163842
#define NLO 40962
#define EPS_GN 1e-5f
#define SLOPE 0.2f

typedef __attribute__((ext_vector_type(8))) short short8;
typedef __attribute__((ext_vector_type(16))) float f32x16;

__device__ inline ushort f2bf(float f) {
    union { float f; unsigned u; } v; v.f = f;
    unsigned r = v.u + 0x7FFF + ((v.u >> 16) & 1);
    return (ushort)(r >> 16);
}
__device__ inline float bf2f(ushort h) {
    union { unsigned u; float f; } v; v.u = ((unsigned)h) << 16;
    return v.f;
}

// async global->LDS, 16B per lane; LDS dest = wave base + lane*16
__device__ inline void glds16(const ushort* g, ushort* l) {
    typedef __attribute__((address_space(1))) const void gv;
    typedef __attribute__((address_space(3))) void lv;
    __builtin_amdgcn_global_load_lds((gv*)g, (lv*)l, 16, 0, 0);
}

// ---------------------------------------------------------------------------
// 1) Transpose x: (B,64,NHI) f32 -> xT (B,NHI,64) bf16
// ---------------------------------------------------------------------------
__global__ void k_transpose_x(const float* __restrict__ x, ushort* __restrict__ xT) {
    __shared__ float t[64][65];
    const int b   = blockIdx.y;
    const int n0  = blockIdx.x * 64;
    const int tid = threadIdx.x;
    const int nq  = tid & 15;
    const int c0  = tid >> 4;
    const bool full = (n0 + 64) <= NHI;
    if (full) {
#pragma unroll
        for (int r = 0; r < 4; ++r) {
            int c = c0 + r * 16;
            float4 v = *(const float4*)&x[((long)b * IN_CH + c) * NHI + n0 + nq * 4];
            t[c][nq * 4 + 0] = v.x; t[c][nq * 4 + 1] = v.y;
            t[c][nq * 4 + 2] = v.z; t[c][nq * 4 + 3] = v.w;
        }
    } else {
        for (int r = 0; r < 4; ++r) {
            int c = c0 + r * 16;
            for (int e = 0; e < 4; ++e) {
                int n = n0 + nq * 4 + e;
                t[c][nq * 4 + e] = (n < NHI) ? x[((long)b * IN_CH + c) * NHI + n] : 0.f;
            }
        }
    }
    __syncthreads();
    const int n  = tid >> 2;
    const int cc = (tid & 3) * 16;
    if (n0 + n < NHI) {
        short8 o0, o1;
#pragma unroll
        for (int e = 0; e < 8; ++e) {
            o0[e] = (short)f2bf(t[cc + e][n]);
            o1[e] = (short)f2bf(t[cc + 8 + e][n]);
        }
        ushort* p = &xT[((long)b * NHI + n0 + n) * 64 + cc];
        *(short8*)p = o0;
        *(short8*)(p + 8) = o1;
    }
}

// ---------------------------------------------------------------------------
// 2) Pre-tile weights W (O=128, K) f32 -> Wb bf16, BK=32 image:
//    Wb[koct(=k>>3)][o(128)][e(8)]  (step t occupies koct 4t..4t+3)
// ---------------------------------------------------------------------------
__global__ void k_prep_w(const float* __restrict__ W, ushort* __restrict__ Wb, int K) {
    int i = blockIdx.x * 256 + threadIdx.x;
    if (i >= K * 128) return;
    int k = i / 128, o = i % 128;
    Wb[(long)(k >> 3) * 1024 + o * 8 + (k & 7)] = f2bf(W[(long)o * K + k]);
}

// ---------------------------------------------------------------------------
// 3) Mean pool
// ---------------------------------------------------------------------------
__global__ void k_pool(const ushort* __restrict__ xT, const int* __restrict__ pn,
                       ushort* __restrict__ h1) {
    long t = (long)blockIdx.x * 256 + threadIdx.x;
    const long total = (long)B_SZ * NLO * 8;
    if (t >= total) return;
    int  cq = (int)(t & 7);
    long bn = t >> 3;
    int  n  = (int)(bn % NLO);
    int  b  = (int)(bn / NLO);
    float acc[8] = {};
#pragma unroll
    for (int j = 0; j < 7; ++j) {
        int idx = pn[n * 7 + j];
        short8 v = *(const short8*)&xT[((long)b * NHI + idx) * 64 + cq * 8];
#pragma unroll
        for (int e = 0; e < 8; ++e) acc[e] += bf2f((ushort)v[e]);
    }
    short8 o;
#pragma unroll
    for (int e = 0; e < 8; ++e) o[e] = (short)f2bf(acc[e] * (1.f / 7.f));
    *(short8*)&h1[bn * 64 + cq * 8] = o;
}

// Swizzled A-image index (R11-verified family): kg in [0,4), nn in [0,128).
// Writes: 8-lane group (2 nodes x 4 kq) -> 8 distinct bank-quads.
// Reads: 8 consecutive nn -> 8 distinct bank-quads (2-way max over 32 lanes = free).
__device__ inline int aidx(int kg, int nn) {
    return (kg * 128 + (nn ^ (kg << 1))) * 8;
}

// ---------------------------------------------------------------------------
// 4) MFMA one-ring conv — R11 schedule at BK=32 for MAX OCCUPANCY.
//    Evidence: conv speed tracks waves/CU monotonically (8w:99us, 12w:97,
//    16w:85-90) regardless of structure -> latency-bound random gather,
//    TLP is the lever. BK=32 shrinks LDS to 33KB/block (A 2x8KB + B 2x8KB)
//    -> 3-4 blocks x 8 waves = 24-32 waves/CU (R11: 16).
//    Block 128 nodes x 128 outs, 512 thr, wave tile 32x64 (acc=32 VGPR),
//    one barrier/step, A reg-staged (1 short8/thread), B via glds DMA.
// ---------------------------------------------------------------------------
template <int CIN>
__global__ __launch_bounds__(512, 6)
void k_conv_mfma(const ushort* __restrict__ src, const int* __restrict__ nbr,
                 const ushort* __restrict__ Wb, const float* __restrict__ bias,
                 ushort* __restrict__ out, float* __restrict__ part) {
    constexpr int NSTEP = 7 * CIN / 32;
    __shared__ ushort Asm[2][4096];   // 8KB/buf, swizzled [kg(4)][nn(128)][e(8)]
    __shared__ ushort Bsm[2][4096];   // 8KB/buf, linear   [kg(4)][o(128)][e(8)]
    __shared__ float  red[8][4];

    const int b    = blockIdx.y;
    const int n0   = blockIdx.x * 128;
    const int tid  = threadIdx.x;
    const int lane = tid & 63;
    const int wave = tid >> 6;               // 0..7
    const int wr   = wave >> 1, wc = wave & 1;
    const int l31  = lane & 31;
    const int khalf = lane >> 5;

    // A staging: 4 threads per node row, one 16B chunk each (32ch window/step)
    const int s_nn = tid >> 2;               // 0..127
    const int s_kq = tid & 3;
    int nrow = n0 + s_nn; if (nrow >= NLO) nrow = NLO - 1;
    int nb[7];
#pragma unroll
    for (int j = 0; j < 7; ++j) nb[j] = nbr[nrow * 7 + j];

    const long srcb = (long)b * NLO * CIN;
    f32x16 acc0 = {}, acc1 = {};
    const int arow = wr * 32 + l31;
    const int bcol = wc * 64 + l31;
    short8 a;

    auto loadA = [&](int t) {
        int j, cb;
        if (CIN == 64) { j = t >> 1; cb = (t & 1) * 32; }
        else           { j = t >> 2; cb = (t & 3) * 32; }
        a = *(const short8*)&src[srcb + (long)nb[j] * CIN + cb + s_kq * 8];
    };

    // prologue: B(0) DMA into buf0; A(0) -> reg
    glds16(&Wb[tid * 8], &Bsm[0][tid * 8]);
    loadA(0);

    for (int t = 0; t < NSTEP; ++t) {
        const int cur = t & 1;
        *(short8*)&Asm[cur][aidx(s_kq, s_nn)] = a;   // A(t) -> LDS
        __syncthreads();    // drains B(t) DMA + A(t) writes; prev reads done
        if (t + 1 < NSTEP) {
            glds16(&Wb[(long)(t + 1) * 4096 + tid * 8], &Bsm[cur ^ 1][tid * 8]);
            loadA(t + 1);   // gather prefetch, lands before next ds_write
        }
#pragma unroll
        for (int kh = 0; kh < 2; ++kh) {
            const int kg = 2 * kh + khalf;
            short8 af = *(const short8*)&Asm[cur][aidx(kg, arow)];
            short8 b0 = *(const short8*)&Bsm[cur][(kg * 128 + bcol) * 8];
            short8 b1 = *(const short8*)&Bsm[cur][(kg * 128 + bcol + 32) * 8];
            acc0 = __builtin_amdgcn_mfma_f32_32x32x16_bf16(af, b0, acc0, 0, 0, 0);
            acc1 = __builtin_amdgcn_mfma_f32_32x32x16_bf16(af, b1, acc1, 0, 0, 0);
        }
        // single barrier per step: next iter writes the other buffer.
    }

    // epilogue: bias, bf16 store, per-block GroupNorm partials (R11-verified)
    const float bias0 = bias[wc * 64 + l31];
    const float bias1 = bias[wc * 64 + 32 + l31];
    float s0 = 0.f, q0 = 0.f, s1 = 0.f, q1 = 0.f;
#pragma unroll
    for (int r = 0; r < 16; ++r) {
        int rrow = (r & 3) + 8 * (r >> 2) + 4 * khalf + wr * 32;
        int n = n0 + rrow;
        float v0 = acc0[r] + bias0;
        float v1 = acc1[r] + bias1;
        if (n < NLO) {
            long o = ((long)b * NLO + n) * 128 + wc * 64 + l31;
            out[o]      = f2bf(v0);
            out[o + 32] = f2bf(v1);
            s0 += v0; q0 += v0 * v0;
            s1 += v1; q1 += v1 * v1;
        }
    }
#pragma unroll
    for (int off = 32; off > 0; off >>= 1) {
        s0 += __shfl_down(s0, off); q0 += __shfl_down(q0, off);
        s1 += __shfl_down(s1, off); q1 += __shfl_down(q1, off);
    }
    if (lane == 0) { red[wave][0] = s0; red[wave][1] = q0; red[wave][2] = s1; red[wave][3] = q1; }
    __syncthreads();
    if (tid < 8) {
        int g = tid >> 1, isq = tid & 1;
        int wcg = g >> 1, ct = g & 1;
        float v = 0.f;
#pragma unroll
        for (int w = 0; w < 4; ++w) v += red[w * 2 + wcg][ct * 2 + isq];
        part[(((long)b * gridDim.x + blockIdx.x) * 4 + g) * 2 + isq] = v;
    }
}

// ---------------------------------------------------------------------------
// 5) Finalize stats -> per (b,c) scale/shift. One block per (b,g).
// ---------------------------------------------------------------------------
__global__ void k_finalize(const float* __restrict__ part, int nblk,
                           const float* __restrict__ w, const float* __restrict__ bb,
                           float* __restrict__ scale, float* __restrict__ shift) {
    const int b = blockIdx.x >> 2, g = blockIdx.x & 3;
    const int tid = threadIdx.x;
    float s = 0.f, ss = 0.f;
    for (int k = tid; k < nblk; k += 256) {
        s  += part[(((long)b * nblk + k) * 4 + g) * 2 + 0];
        ss += part[(((long)b * nblk + k) * 4 + g) * 2 + 1];
    }
#pragma unroll
    for (int off = 32; off > 0; off >>= 1) {
        s += __shfl_down(s, off); ss += __shfl_down(ss, off);
    }
    __shared__ float red[8];
    __shared__ float fin[2];
    const int wave = tid >> 6, lane = tid & 63;
    if (lane == 0) { red[wave * 2] = s; red[wave * 2 + 1] = ss; }
    __syncthreads();
    if (tid == 0) {
        float as = red[0] + red[2] + red[4] + red[6];
        float aq = red[1] + red[3] + red[5] + red[7];
        const float cnt = 32.f * NLO;
        float mu  = as / cnt;
        float var = aq / cnt - mu * mu;
        fin[0] = mu; fin[1] = rsqrtf(var + EPS_GN);
    }
    __syncthreads();
    if (tid < 32) {
        int c = g * 32 + tid;
        float sc = fin[1] * w[c];
        scale[b * 128 + c] = sc;
        shift[b * 128 + c] = bb[c] - fin[0] * sc;
    }
}

// ---------------------------------------------------------------------------
// 6) Elementwise gn+leakyrelu: y (B,NLO,128) bf16 -> yp bf16
// ---------------------------------------------------------------------------
__global__ void k_gnapply(const ushort* __restrict__ y, const float* __restrict__ sc,
                          const float* __restrict__ sh, ushort* __restrict__ yp) {
    long t = (long)blockIdx.x * 256 + threadIdx.x;
    const long total = (long)B_SZ * NLO * 16;
    if (t >= total) return;
    int  c8 = (int)(t & 15);
    long bn = t >> 4;
    int  b  = (int)(bn / NLO);
    short8 v = *(const short8*)&y[bn * 128 + c8 * 8];
    short8 o;
#pragma unroll
    for (int e = 0; e < 8; ++e) {
        int c = c8 * 8 + e;
        float f = bf2f((ushort)v[e]) * sc[b * 128 + c] + sh[b * 128 + c];
        f = fmaxf(f, SLOPE * f);
        o[e] = (short)f2bf(f);
    }
    *(short8*)&yp[bn * 128 + c8 * 8] = o;
}

// ---------------------------------------------------------------------------
// 7) Output: gn2 + leakyrelu + transpose (B,N,128) bf16 -> (B,128,N) f32
// ---------------------------------------------------------------------------
__global__ void k_output(const ushort* __restrict__ y2, const float* __restrict__ scale,
                         const float* __restrict__ shift, float* __restrict__ out) {
    __shared__ float t[32][129];
    const int b   = blockIdx.y;
    const int n0  = blockIdx.x * 32;
    const int tid = threadIdx.x;
    const float* scb = &scale[b * 128];
    const float* shb = &shift[b * 128];
    const int c8 = (tid & 15) * 8;
#pragma unroll
    for (int r = 0; r < 2; ++r) {
        int nn = (tid >> 4) + r * 16;
        int n  = n0 + nn;
        if (n < NLO) {
            short8 v = *(const short8*)&y2[((long)b * NLO + n) * 128 + c8];
#pragma unroll
            for (int e = 0; e < 8; ++e) {
                int c = c8 + e;
                float f = bf2f((ushort)v[e]) * scb[c] + shb[c];
                t[nn][c] = fmaxf(f, SLOPE * f);
            }
        } else {
#pragma unroll
            for (int e = 0; e < 8; ++e) t[nn][c8 + e] = 0.f;
        }
    }
    __syncthreads();
    const int n4 = (tid & 7) * 4;
    const bool full = (n0 + 32) <= NLO;
#pragma unroll
    for (int r = 0; r < 4; ++r) {
        int c = (tid >> 3) + r * 32;
        long o = ((long)b * 128 + c) * NLO + n0 + n4;
        if (full) {
            float2 v0 = make_float2(t[n4][c], t[n4 + 1][c]);
            float2 v1 = make_float2(t[n4 + 2][c], t[n4 + 3][c]);
            *(float2*)&out[o]     = v0;
            *(float2*)&out[o + 2] = v1;
        } else {
            for (int e = 0; e < 4; ++e)
                if (n0 + n4 + e < NLO) out[o + e] = t[n4 + e][c];
        }
    }
}

// ---------------------------------------------------------------------------
// Launch
// ---------------------------------------------------------------------------
extern "C" void kernel_launch(void* const* d_in, const int* in_sizes, int n_in,
                              void* d_out, int out_size, void* d_ws, size_t ws_size,
                              hipStream_t stream) {
    const float* x   = (const float*)d_in[0];
    const int*   pn  = (const int*)d_in[1];
    const int*   cn  = (const int*)d_in[2];
    const float* W1  = (const float*)d_in[3];
    const float* b1  = (const float*)d_in[4];
    const float* g1w = (const float*)d_in[5];
    const float* g1b = (const float*)d_in[6];
    const float* W2  = (const float*)d_in[7];
    const float* b2  = (const float*)d_in[8];
    const float* g2w = (const float*)d_in[9];
    const float* g2b = (const float*)d_in[10];
    float* out = (float*)d_out;
    char*  base = (char*)d_ws;

    ushort* xT  = (ushort*)(base + 0);           // 83,887,104 B
    ushort* y1  = (ushort*)(base + 0);           // reuse (xT dead after pool)
    ushort* y1p = (ushort*)(base + 44000000);
    ushort* h1  = (ushort*)(base + 88000000);
    ushort* y2  = (ushort*)(base + 110000000);
    ushort* wb1 = (ushort*)(base + 152000000);
    ushort* wb2 = (ushort*)(base + 152200000);
    float*  p1  = (float*)(base + 152500000);
    float*  p2  = (float*)(base + 152600000);
    float*  sc1 = (float*)(base + 152700000);
    float*  sh1 = sc1 + 512;
    float*  sc2 = (float*)(base + 152710000);
    float*  sh2 = sc2 + 512;

    const int NBLK = (NLO + 127) / 128;  // 321 conv blocks per batch

    k_transpose_x<<<dim3((NHI + 63) / 64, B_SZ), 256, 0, stream>>>(x, xT);
    k_prep_w<<<(448 * 128 + 255) / 256, 256, 0, stream>>>(W1, wb1, 448);
    k_prep_w<<<(896 * 128 + 255) / 256, 256, 0, stream>>>(W2, wb2, 896);
    k_pool<<<(int)(((long)B_SZ * NLO * 8 + 255) / 256), 256, 0, stream>>>(xT, pn, h1);
    k_conv_mfma<64><<<dim3(NBLK, B_SZ), 512, 0, stream>>>(h1, cn, wb1, b1, y1, p1);
    k_finalize<<<16, 256, 0, stream>>>(p1, NBLK, g1w, g1b, sc1, sh1);
    k_gnapply<<<(int)(((long)B_SZ * NLO * 16 + 255) / 256), 256, 0, stream>>>(y1, sc1, sh1, y1p);
    k_conv_mfma<128><<<dim3(NBLK, B_SZ), 512, 0, stream>>>(y1p, cn, wb2, b2, y2, p2);
    k_finalize<<<16, 256, 0, stream>>>(p2, NBLK, g2w, g2b, sc2, sh2);
    k_output<<<dim3((NLO + 31) / 32, B_SZ), 256, 0, stream>>>(y2, sc2, sh2, out);
}